// Round 2
// baseline (377.133 us; speedup 1.0000x reference)
//
#include <hip/hip_runtime.h>
#include <hip/hip_bf16.h>

// MultiheadAttention: x[4,2048,1024] fp32 -> out fp32. Internal bf16 MFMA.
// R15: attn_k LDS overhaul (R14 post-mortem: 2.5e7 bank-conflict cycles = 25%
// of kernel; LDS pipe critical path from 4x-redundant K/V reads).
//   - LD=72 pad -> LD=64 + XOR chunk swizzle (chunk^=(row&7)); staged via
//     global_load_lds with LINEAR dest + inverse-swizzled per-lane SOURCE
//     (rule 21 / m201 pattern, same form as qkv_gemm reads = proven low-conflict).
//   - wave owns 32 q (2 groups), block = 128 q: every kf/vf LDS read feeds
//     2 MFMAs -> LDS:MFMA cycle ratio ~1:1 (was 2:1). K redundancy 4x -> 2x/q.
//   - Q fragments loaded direct from global (b128, contiguous in d); Q LDS
//     staging + its barrier deleted.
//   - K/V double-buffered (2x16KB): one barrier per tile, staging overlaps
//     compute (gload_lds drained by compiler vmcnt(0)@barrier).
//   - per-kt softmax interleave (sc lifetime short -> VGPR ~95, lb(256,5)).
// gemm stays R11/R12 (256x128, BK=64, global_load_lds).

#define DIM  1024
#define SEQ  2048
#define BATCH 4
#define NH   16
#define HD   64

typedef __bf16 bf16x8 __attribute__((ext_vector_type(8)));
typedef short  s16x4  __attribute__((ext_vector_type(4)));
typedef float  f32x4  __attribute__((ext_vector_type(4)));
typedef unsigned int uint4v __attribute__((ext_vector_type(4)));

static __device__ __forceinline__ f32x4 mfma16(s16x4 a, s16x4 b, f32x4 c) {
    return __builtin_amdgcn_mfma_f32_16x16x16bf16_1k(a, b, c, 0, 0, 0);
}

static __device__ __forceinline__ unsigned short f2b(float f) {
    __bf16 h = (__bf16)f;                      // RNE convert
    return __builtin_bit_cast(unsigned short, h);
}

static __device__ __forceinline__ void load_lds16(const unsigned short* g,
                                                  unsigned short* l) {
    __builtin_amdgcn_global_load_lds(
        (const __attribute__((address_space(1))) void*)g,
        (__attribute__((address_space(3))) void*)l, 16, 0, 0);
}

// ---------------------------------------------------------------------------
// Kernel A: x fp32 -> bf16. 8,388,608 elems -> 4096 blocks.
// ---------------------------------------------------------------------------
__global__ __launch_bounds__(256) void cvt_x_k(const float* __restrict__ x,
                                               unsigned short* __restrict__ xb) {
    size_t i = ((size_t)blockIdx.x * 256 + threadIdx.x) * 8;
    const f32x4* s = (const f32x4*)(x + i);
    f32x4 a0 = s[0], a1 = s[1];
    bf16x8 v;
    for (int j = 0; j < 4; j++) { v[j] = (__bf16)a0[j]; v[4 + j] = (__bf16)a1[j]; }
    *(bf16x8*)(xb + i) = v;
}

// ---------------------------------------------------------------------------
// Kernel 0: Wt[n][k] = bf16(W[k][n]) for z = 0,1,2 (Wq,Wk,Wv). fp32 input.
// ---------------------------------------------------------------------------
__global__ void transpose_w_k(const float* __restrict__ Wq,
                              const float* __restrict__ Wk,
                              const float* __restrict__ Wv,
                              unsigned short* __restrict__ Wt) {
    __shared__ unsigned short t[32][33];
    int z = blockIdx.z;
    const float* W = (z == 0) ? Wq : (z == 1) ? Wk : Wv;
    unsigned short* o = Wt + (size_t)z * DIM * DIM;
    int tx = threadIdx.x;
    int n0 = blockIdx.x * 32, k0 = blockIdx.y * 32;
    for (int j = threadIdx.y; j < 32; j += 8)
        t[j][tx] = f2b(W[(size_t)(k0 + j) * DIM + n0 + tx]);
    __syncthreads();
    for (int j = threadIdx.y; j < 32; j += 8)
        o[(size_t)(n0 + j) * DIM + k0 + tx] = t[tx][j];
}

// ---------------------------------------------------------------------------
// Kernel 1: fused QKV projection (R11/R12, unchanged). grid (8, 32, 3), 512 thr.
// 256x128 tile, BK=64. global_load_lds + XOR swizzle chunk^=(row&7).
// z=0 -> Q scaled log2e/8, z=1 -> K, z=2 -> V^T via per-wave LDS transpose.
// ---------------------------------------------------------------------------
__global__ __launch_bounds__(512) void qkv_gemm_k(
    const unsigned short* __restrict__ xb,
    const unsigned short* __restrict__ WtBase,
    const float* __restrict__ bq,
    const float* __restrict__ bk,
    const float* __restrict__ bv,
    unsigned short* __restrict__ Qo,
    unsigned short* __restrict__ Ko,
    unsigned short* __restrict__ Vto) {
    __shared__ __align__(16) unsigned short As[256 * 64];   // 32 KB, NO pad
    __shared__ __align__(16) unsigned short Bs[128 * 64];   // 16 KB
    int tid = threadIdx.x, wave = tid >> 6, lane = tid & 63;
    int quad = lane >> 4, lc = lane & 15;
    int m0 = blockIdx.y * 256, n0 = blockIdx.x * 128;
    int z = blockIdx.z;
    const unsigned short* Wt = WtBase + (size_t)z * DIM * DIM;
    int wm = (wave >> 1) * 64, wn = (wave & 1) * 64;
    int swzlo = lc & 7;

    f32x4 acc[4][4] = {};

    for (int k0 = 0; k0 < DIM; k0 += 64) {
        __syncthreads();
        #pragma unroll
        for (int p = 0; p < 4; p++) {
            int c = tid + p * 512, r = c >> 3, cc = (c & 7) ^ (r & 7);
            load_lds16(xb + (size_t)(m0 + r) * DIM + k0 + cc * 8, &As[c * 8]);
        }
        #pragma unroll
        for (int p = 0; p < 2; p++) {
            int c = tid + p * 512, r = c >> 3, cc = (c & 7) ^ (r & 7);
            load_lds16(Wt + (size_t)(n0 + r) * DIM + k0 + cc * 8, &Bs[c * 8]);
        }
        __syncthreads();
        #pragma unroll
        for (int kk = 0; kk < 2; kk++) {
            int off = ((kk * 4 + quad) ^ swzlo) * 8;
            bf16x8 af[4], bfr[4];
            for (int mt = 0; mt < 4; mt++)
                af[mt] = *(const bf16x8*)&As[(wm + mt * 16 + lc) * 64 + off];
            for (int nt = 0; nt < 4; nt++)
                bfr[nt] = *(const bf16x8*)&Bs[(wn + nt * 16 + lc) * 64 + off];
            for (int mt = 0; mt < 4; mt++)
                for (int nt = 0; nt < 4; nt++)
                    acc[mt][nt] = __builtin_amdgcn_mfma_f32_16x16x32_bf16(
                        af[mt], bfr[nt], acc[mt][nt], 0, 0, 0);
        }
    }

    const float* bias = (z == 0) ? bq : (z == 1) ? bk : bv;
    float scale = (z == 0) ? 0.18033688011112042f : 1.0f;  // (1/8)*log2(e)

    if (z != 2) {
        for (int nt = 0; nt < 4; nt++) {
            int n = n0 + wn + nt * 16 + lc;
            float bvl = bias[n];
            int h = n >> 6, d = n & 63;
            for (int mt = 0; mt < 4; mt++) {
                for (int r = 0; r < 4; r++) {
                    int m = m0 + wm + mt * 16 + quad * 4 + r;
                    int b = m >> 11, s = m & 2047;
                    unsigned short ub = f2b((acc[mt][nt][r] + bvl) * scale);
                    if (z == 0)
                        Qo[((size_t)(b * NH + h) * SEQ + s) * HD + d] = ub;
                    else
                        Ko[((size_t)(b * NH + h) * SEQ + s) * HD + d] = ub;
                }
            }
        }
    } else {
        // V^T: per-wave LDS transpose (16 m x 64 n slices), coalesced stores.
        __syncthreads();
        unsigned short* T = As + wave * 1024;
        int h = (n0 + wn) >> 6;
        int d = lane;
        for (int mt = 0; mt < 4; mt++) {
            for (int nt = 0; nt < 4; nt++) {
                int n = n0 + wn + nt * 16 + lc;
                float bvl = bias[n];
                s16x4 v4;
                for (int r = 0; r < 4; r++)
                    v4[r] = (short)f2b(acc[mt][nt][r] + bvl);
                *(s16x4*)&T[(nt * 16 + lc) * 16 + quad * 4] = v4;
            }
            int s_base = m0 + wm + mt * 16;
            int b = s_base >> 11, sl = s_base & 2047;
            unsigned short* dst =
                Vto + ((size_t)(b * NH + h) * HD + d) * SEQ + sl;
            uint4v t0 = *(const uint4v*)&T[d * 16];
            uint4v t1 = *(const uint4v*)&T[d * 16 + 8];
            *(uint4v*)&dst[0] = t0;
            *(uint4v*)&dst[8] = t1;
        }
    }
}

// ---------------------------------------------------------------------------
// Kernel 2: flash attention (R15). grid (16,16,4), 256 thr (4 waves).
// Block = 128 q. Wave w owns q rows w*32 + g*16 + lc, g=0,1 (2 groups).
// K/V tiles (64 keys) double-buffered in LDS, XOR-swizzled, gload_lds-staged.
// Q fragments direct from global. Score C-layout == K=16 PV B-layout.
// ---------------------------------------------------------------------------
__global__ __launch_bounds__(256, 5) void attn_k(
    const unsigned short* __restrict__ Q,
    const unsigned short* __restrict__ K,
    const unsigned short* __restrict__ Vt,
    float* __restrict__ out) {
    // 2 buffers x (K 64x64 + V^T 64x64) shorts = 2 x 16 KB
    __shared__ __align__(16) unsigned short KV[2 * 8192];

    int tid = threadIdx.x, wave = tid >> 6, lane = tid & 63;
    int quad = lane >> 4, lc = lane & 15;
    int swz = lc & 7;
    int b = blockIdx.z, h = blockIdx.y, qt = blockIdx.x;
    int bh = b * NH + h;
    const unsigned short* Qg = Q + ((size_t)bh * SEQ + qt * 128) * HD;
    const unsigned short* Kg = K + (size_t)bh * SEQ * HD;
    const unsigned short* Vg = Vt + (size_t)bh * HD * SEQ;

    // Q fragments direct from global: B[k=d=ks*32+quad*8+j][n=q=g*16+lc]
    bf16x8 qf0[2], qf1[2];
    {
        const unsigned short* q0 = Qg + (size_t)(wave * 32 + lc) * HD + quad * 8;
        const unsigned short* q1 = q0 + 16 * HD;
        qf0[0] = *(const bf16x8*)q0;  qf0[1] = *(const bf16x8*)(q0 + 32);
        qf1[0] = *(const bf16x8*)q1;  qf1[1] = *(const bf16x8*)(q1 + 32);
    }

    f32x4 o[4][2] = {};   // [dt][g]: O^T[d=dt*16+quad*4+r][q=g*16+lc]
    float rsum0 = 0.0f, rsum1 = 0.0f;

    // prologue: stage tile 0 into buffer 0 (linear dest, swizzled source)
    {
        unsigned short* Ks = KV;
        unsigned short* Vs = KV + 4096;
        #pragma unroll
        for (int p = 0; p < 2; p++) {
            int c = tid + p * 256, r = c >> 3, cc = c & 7;
            int sc8 = (cc ^ (r & 7)) * 8;
            load_lds16(Kg + (size_t)r * HD + sc8, &Ks[c * 8]);
            load_lds16(Vg + (size_t)r * SEQ + sc8, &Vs[c * 8]);
        }
    }

    for (int t0 = 0; t0 < SEQ; t0 += 64) {
        int cur = (t0 >> 6) & 1;
        unsigned short* Ks = KV + cur * 8192;
        unsigned short* Vs = Ks + 4096;
        __syncthreads();   // drains prior gload_lds (compiler vmcnt(0)) + read/write hazard

        if (t0 + 64 < SEQ) {   // stage next tile into other buffer; overlaps compute
            unsigned short* Kn = KV + (cur ^ 1) * 8192;
            unsigned short* Vn = Kn + 4096;
            #pragma unroll
            for (int p = 0; p < 2; p++) {
                int c = tid + p * 256, r = c >> 3, cc = c & 7;
                int sc8 = (cc ^ (r & 7)) * 8;
                load_lds16(Kg + (size_t)(t0 + 64 + r) * HD + sc8, &Kn[c * 8]);
                load_lds16(Vg + (size_t)r * SEQ + (t0 + 64) + sc8, &Vn[c * 8]);
            }
        }

        // QK^T + softmax numerator, per kt (keeps sc lifetime short)
        s16x4 pf[4][2];
        __builtin_amdgcn_s_setprio(1);
        #pragma unroll
        for (int kt = 0; kt < 4; kt++) {
            f32x4 sA = {}, sB = {};
            #pragma unroll
            for (int ks = 0; ks < 2; ks++) {
                bf16x8 kf = *(const bf16x8*)
                    &Ks[(kt * 16 + lc) * 64 + ((ks * 4 + quad) ^ swz) * 8];
                sA = __builtin_amdgcn_mfma_f32_16x16x32_bf16(kf, qf0[ks], sA, 0, 0, 0);
                sB = __builtin_amdgcn_mfma_f32_16x16x32_bf16(kf, qf1[ks], sB, 0, 0, 0);
            }
            #pragma unroll
            for (int r = 0; r < 4; r++) {
                float pa = __builtin_amdgcn_exp2f(sA[r]);
                float pb = __builtin_amdgcn_exp2f(sB[r]);
                rsum0 += pa; rsum1 += pb;
                pf[kt][0][r] = (short)f2b(pa);
                pf[kt][1][r] = (short)f2b(pb);
            }
        }

        // PV: o[dt][g] += V^T[d][key] * P[key][q]  (K=16, P register-resident)
        #pragma unroll
        for (int dt = 0; dt < 4; dt++) {
            #pragma unroll
            for (int kt = 0; kt < 4; kt++) {
                s16x4 vf = *(const s16x4*)
                    &Vs[(dt * 16 + lc) * 64 +
                        ((2 * kt + (quad >> 1)) ^ swz) * 8 + (quad & 1) * 4];
                o[dt][0] = mfma16(vf, pf[kt][0], o[dt][0]);
                o[dt][1] = mfma16(vf, pf[kt][1], o[dt][1]);
            }
        }
        __builtin_amdgcn_s_setprio(0);
    }

    // denominator: reduce partials across quads (same q = lc)
    rsum0 += __shfl_xor(rsum0, 16); rsum0 += __shfl_xor(rsum0, 32);
    rsum1 += __shfl_xor(rsum1, 16); rsum1 += __shfl_xor(rsum1, 32);
    float inv0 = 1.0f / rsum0, inv1 = 1.0f / rsum1;

    // direct stores: row q = qt*128 + wave*32 + g*16 + lc, cols h*64+dt*16+quad*4
    float* o0 = out + ((size_t)b * SEQ + qt * 128 + wave * 32 + lc) * DIM
                + h * HD + quad * 4;
    float* o1 = o0 + (size_t)16 * DIM;
    #pragma unroll
    for (int dt = 0; dt < 4; dt++) {
        f32x4 s0 = o[dt][0]; s0 *= inv0;
        f32x4 s1 = o[dt][1]; s1 *= inv1;
        *(f32x4*)&o0[dt * 16] = s0;
        *(f32x4*)&o1[dt * 16] = s1;
    }
}

// ---------------------------------------------------------------------------
extern "C" void kernel_launch(void* const* d_in, const int* in_sizes, int n_in,
                              void* d_out, int out_size, void* d_ws, size_t ws_size,
                              hipStream_t stream) {
    (void)in_sizes; (void)n_in; (void)out_size; (void)ws_size;
    const float* x  = (const float*)d_in[0];
    const float* Wq = (const float*)d_in[1];
    const float* bq = (const float*)d_in[2];
    const float* Wk = (const float*)d_in[3];
    const float* bk = (const float*)d_in[4];
    const float* Wv = (const float*)d_in[5];
    const float* bv = (const float*)d_in[6];

    char* ws = (char*)d_ws;
    unsigned short* Wt = (unsigned short*)ws;                             // 6 MB
    unsigned short* Qb = (unsigned short*)(ws + (size_t)6 * 1024 * 1024);
    unsigned short* Kb = Qb + (size_t)BATCH * NH * SEQ * HD;
    unsigned short* Vb = Kb + (size_t)BATCH * NH * SEQ * HD;
    unsigned short* xb = (unsigned short*)d_out;  // scratch; attn overwrites

    cvt_x_k<<<dim3(4096), dim3(256), 0, stream>>>(x, xb);
    transpose_w_k<<<dim3(32, 32, 3), dim3(32, 8), 0, stream>>>(Wq, Wk, Wv, Wt);
    qkv_gemm_k<<<dim3(8, 32, 3), dim3(512), 0, stream>>>(xb, Wt, bq, bk, bv, Qb, Kb, Vb);
    attn_k<<<dim3(16, NH, BATCH), dim3(256), 0, stream>>>(Qb, Kb, Vb, (float*)d_out);
}

// Round 3
// 258.976 us; speedup vs baseline: 1.4562x; 1.4562x over previous
//
#include <hip/hip_runtime.h>
#include <hip/hip_bf16.h>

// MultiheadAttention: x[4,2048,1024] fp32 -> out fp32. Internal bf16 MFMA.
// R16: fix R15's two regressions, keep its compute structure verbatim.
//   POST-MORTEM R15: WRITE_SIZE 441 MB (out is 33.5 MB) + VGPR_Count=48 =>
//   scratch spills. This toolchain's __launch_bounds__ 2nd arg is in units of
//   32-thread warps: cap = 512/(2*arg). (256,5) capped at 48 VGPRs and spilled
//   the o/qf/pf register state every tile. R14's (256,7)->36 confirms formula.
//   - attn_k: __launch_bounds__(256) only (R13 style, measured VGPR=100, no
//     spills). Natural ~4 waves/SIMD.
//   - XCD-aware 1D grid (1024 blocks): bid&7 = XCD; each XCD owns 8 bh
//     (4 MB K/V = its L2). FETCH predicted 273 -> ~60 MB.
// gemm stays R11/R12 (256x128, BK=64, global_load_lds).

#define DIM  1024
#define SEQ  2048
#define BATCH 4
#define NH   16
#define HD   64

typedef __bf16 bf16x8 __attribute__((ext_vector_type(8)));
typedef short  s16x4  __attribute__((ext_vector_type(4)));
typedef float  f32x4  __attribute__((ext_vector_type(4)));
typedef unsigned int uint4v __attribute__((ext_vector_type(4)));

static __device__ __forceinline__ f32x4 mfma16(s16x4 a, s16x4 b, f32x4 c) {
    return __builtin_amdgcn_mfma_f32_16x16x16bf16_1k(a, b, c, 0, 0, 0);
}

static __device__ __forceinline__ unsigned short f2b(float f) {
    __bf16 h = (__bf16)f;                      // RNE convert
    return __builtin_bit_cast(unsigned short, h);
}

static __device__ __forceinline__ void load_lds16(const unsigned short* g,
                                                  unsigned short* l) {
    __builtin_amdgcn_global_load_lds(
        (const __attribute__((address_space(1))) void*)g,
        (__attribute__((address_space(3))) void*)l, 16, 0, 0);
}

// ---------------------------------------------------------------------------
// Kernel A: x fp32 -> bf16. 8,388,608 elems -> 4096 blocks.
// ---------------------------------------------------------------------------
__global__ __launch_bounds__(256) void cvt_x_k(const float* __restrict__ x,
                                               unsigned short* __restrict__ xb) {
    size_t i = ((size_t)blockIdx.x * 256 + threadIdx.x) * 8;
    const f32x4* s = (const f32x4*)(x + i);
    f32x4 a0 = s[0], a1 = s[1];
    bf16x8 v;
    for (int j = 0; j < 4; j++) { v[j] = (__bf16)a0[j]; v[4 + j] = (__bf16)a1[j]; }
    *(bf16x8*)(xb + i) = v;
}

// ---------------------------------------------------------------------------
// Kernel 0: Wt[n][k] = bf16(W[k][n]) for z = 0,1,2 (Wq,Wk,Wv). fp32 input.
// ---------------------------------------------------------------------------
__global__ void transpose_w_k(const float* __restrict__ Wq,
                              const float* __restrict__ Wk,
                              const float* __restrict__ Wv,
                              unsigned short* __restrict__ Wt) {
    __shared__ unsigned short t[32][33];
    int z = blockIdx.z;
    const float* W = (z == 0) ? Wq : (z == 1) ? Wk : Wv;
    unsigned short* o = Wt + (size_t)z * DIM * DIM;
    int tx = threadIdx.x;
    int n0 = blockIdx.x * 32, k0 = blockIdx.y * 32;
    for (int j = threadIdx.y; j < 32; j += 8)
        t[j][tx] = f2b(W[(size_t)(k0 + j) * DIM + n0 + tx]);
    __syncthreads();
    for (int j = threadIdx.y; j < 32; j += 8)
        o[(size_t)(n0 + j) * DIM + k0 + tx] = t[tx][j];
}

// ---------------------------------------------------------------------------
// Kernel 1: fused QKV projection (R11/R12, unchanged). grid (8, 32, 3), 512 thr.
// 256x128 tile, BK=64. global_load_lds + XOR swizzle chunk^=(row&7).
// z=0 -> Q scaled log2e/8, z=1 -> K, z=2 -> V^T via per-wave LDS transpose.
// ---------------------------------------------------------------------------
__global__ __launch_bounds__(512) void qkv_gemm_k(
    const unsigned short* __restrict__ xb,
    const unsigned short* __restrict__ WtBase,
    const float* __restrict__ bq,
    const float* __restrict__ bk,
    const float* __restrict__ bv,
    unsigned short* __restrict__ Qo,
    unsigned short* __restrict__ Ko,
    unsigned short* __restrict__ Vto) {
    __shared__ __align__(16) unsigned short As[256 * 64];   // 32 KB, NO pad
    __shared__ __align__(16) unsigned short Bs[128 * 64];   // 16 KB
    int tid = threadIdx.x, wave = tid >> 6, lane = tid & 63;
    int quad = lane >> 4, lc = lane & 15;
    int m0 = blockIdx.y * 256, n0 = blockIdx.x * 128;
    int z = blockIdx.z;
    const unsigned short* Wt = WtBase + (size_t)z * DIM * DIM;
    int wm = (wave >> 1) * 64, wn = (wave & 1) * 64;
    int swzlo = lc & 7;

    f32x4 acc[4][4] = {};

    for (int k0 = 0; k0 < DIM; k0 += 64) {
        __syncthreads();
        #pragma unroll
        for (int p = 0; p < 4; p++) {
            int c = tid + p * 512, r = c >> 3, cc = (c & 7) ^ (r & 7);
            load_lds16(xb + (size_t)(m0 + r) * DIM + k0 + cc * 8, &As[c * 8]);
        }
        #pragma unroll
        for (int p = 0; p < 2; p++) {
            int c = tid + p * 512, r = c >> 3, cc = (c & 7) ^ (r & 7);
            load_lds16(Wt + (size_t)(n0 + r) * DIM + k0 + cc * 8, &Bs[c * 8]);
        }
        __syncthreads();
        #pragma unroll
        for (int kk = 0; kk < 2; kk++) {
            int off = ((kk * 4 + quad) ^ swzlo) * 8;
            bf16x8 af[4], bfr[4];
            for (int mt = 0; mt < 4; mt++)
                af[mt] = *(const bf16x8*)&As[(wm + mt * 16 + lc) * 64 + off];
            for (int nt = 0; nt < 4; nt++)
                bfr[nt] = *(const bf16x8*)&Bs[(wn + nt * 16 + lc) * 64 + off];
            for (int mt = 0; mt < 4; mt++)
                for (int nt = 0; nt < 4; nt++)
                    acc[mt][nt] = __builtin_amdgcn_mfma_f32_16x16x32_bf16(
                        af[mt], bfr[nt], acc[mt][nt], 0, 0, 0);
        }
    }

    const float* bias = (z == 0) ? bq : (z == 1) ? bk : bv;
    float scale = (z == 0) ? 0.18033688011112042f : 1.0f;  // (1/8)*log2(e)

    if (z != 2) {
        for (int nt = 0; nt < 4; nt++) {
            int n = n0 + wn + nt * 16 + lc;
            float bvl = bias[n];
            int h = n >> 6, d = n & 63;
            for (int mt = 0; mt < 4; mt++) {
                for (int r = 0; r < 4; r++) {
                    int m = m0 + wm + mt * 16 + quad * 4 + r;
                    int b = m >> 11, s = m & 2047;
                    unsigned short ub = f2b((acc[mt][nt][r] + bvl) * scale);
                    if (z == 0)
                        Qo[((size_t)(b * NH + h) * SEQ + s) * HD + d] = ub;
                    else
                        Ko[((size_t)(b * NH + h) * SEQ + s) * HD + d] = ub;
                }
            }
        }
    } else {
        // V^T: per-wave LDS transpose (16 m x 64 n slices), coalesced stores.
        __syncthreads();
        unsigned short* T = As + wave * 1024;
        int h = (n0 + wn) >> 6;
        int d = lane;
        for (int mt = 0; mt < 4; mt++) {
            for (int nt = 0; nt < 4; nt++) {
                int n = n0 + wn + nt * 16 + lc;
                float bvl = bias[n];
                s16x4 v4;
                for (int r = 0; r < 4; r++)
                    v4[r] = (short)f2b(acc[mt][nt][r] + bvl);
                *(s16x4*)&T[(nt * 16 + lc) * 16 + quad * 4] = v4;
            }
            int s_base = m0 + wm + mt * 16;
            int b = s_base >> 11, sl = s_base & 2047;
            unsigned short* dst =
                Vto + ((size_t)(b * NH + h) * HD + d) * SEQ + sl;
            uint4v t0 = *(const uint4v*)&T[d * 16];
            uint4v t1 = *(const uint4v*)&T[d * 16 + 8];
            *(uint4v*)&dst[0] = t0;
            *(uint4v*)&dst[8] = t1;
        }
    }
}

// ---------------------------------------------------------------------------
// Kernel 2: flash attention (R16 = R15 loop, no VGPR cap, XCD-banded grid).
// 1024 blocks 1-D, 256 thr (4 waves). Block = 128 q.
// bid&7 = XCD; XCD x owns bh in [x*8, x*8+8) -> 4 MB K/V = one XCD L2.
// Wave w owns q rows w*32 + g*16 + lc, g=0,1. K/V double-buffered LDS,
// XOR-swizzled, gload_lds-staged (linear dest + swizzled source).
// Q fragments direct from global. Score C-layout == K=16 PV B-layout.
// ---------------------------------------------------------------------------
__global__ __launch_bounds__(256) void attn_k(
    const unsigned short* __restrict__ Q,
    const unsigned short* __restrict__ K,
    const unsigned short* __restrict__ Vt,
    float* __restrict__ out) {
    // 2 buffers x (K 64x64 + V^T 64x64) shorts = 2 x 16 KB
    __shared__ __align__(16) unsigned short KV[2 * 8192];

    int tid = threadIdx.x, wave = tid >> 6, lane = tid & 63;
    int quad = lane >> 4, lc = lane & 15;
    int swz = lc & 7;
    // XCD-banded decode: bijective bid -> (bh, qt)
    int bid = blockIdx.x;
    int j = bid >> 3;
    int bh = (bid & 7) * 8 + (j >> 4);
    int qt = j & 15;
    int b = bh >> 4, h = bh & 15;
    const unsigned short* Qg = Q + ((size_t)bh * SEQ + qt * 128) * HD;
    const unsigned short* Kg = K + (size_t)bh * SEQ * HD;
    const unsigned short* Vg = Vt + (size_t)bh * HD * SEQ;

    // Q fragments direct from global: B[k=d=ks*32+quad*8+j][n=q=g*16+lc]
    bf16x8 qf0[2], qf1[2];
    {
        const unsigned short* q0 = Qg + (size_t)(wave * 32 + lc) * HD + quad * 8;
        const unsigned short* q1 = q0 + 16 * HD;
        qf0[0] = *(const bf16x8*)q0;  qf0[1] = *(const bf16x8*)(q0 + 32);
        qf1[0] = *(const bf16x8*)q1;  qf1[1] = *(const bf16x8*)(q1 + 32);
    }

    f32x4 o[4][2] = {};   // [dt][g]: O^T[d=dt*16+quad*4+r][q=g*16+lc]
    float rsum0 = 0.0f, rsum1 = 0.0f;

    // prologue: stage tile 0 into buffer 0 (linear dest, swizzled source)
    {
        unsigned short* Ks = KV;
        unsigned short* Vs = KV + 4096;
        #pragma unroll
        for (int p = 0; p < 2; p++) {
            int c = tid + p * 256, r = c >> 3, cc = c & 7;
            int sc8 = (cc ^ (r & 7)) * 8;
            load_lds16(Kg + (size_t)r * HD + sc8, &Ks[c * 8]);
            load_lds16(Vg + (size_t)r * SEQ + sc8, &Vs[c * 8]);
        }
    }

    for (int t0 = 0; t0 < SEQ; t0 += 64) {
        int cur = (t0 >> 6) & 1;
        unsigned short* Ks = KV + cur * 8192;
        unsigned short* Vs = Ks + 4096;
        __syncthreads();   // drains prior gload_lds (compiler vmcnt(0)) + read/write hazard

        if (t0 + 64 < SEQ) {   // stage next tile into other buffer; overlaps compute
            unsigned short* Kn = KV + (cur ^ 1) * 8192;
            unsigned short* Vn = Kn + 4096;
            #pragma unroll
            for (int p = 0; p < 2; p++) {
                int c = tid + p * 256, r = c >> 3, cc = c & 7;
                int sc8 = (cc ^ (r & 7)) * 8;
                load_lds16(Kg + (size_t)(t0 + 64 + r) * HD + sc8, &Kn[c * 8]);
                load_lds16(Vg + (size_t)r * SEQ + (t0 + 64) + sc8, &Vn[c * 8]);
            }
        }

        // QK^T + softmax numerator, per kt (keeps sc lifetime short)
        s16x4 pf[4][2];
        __builtin_amdgcn_s_setprio(1);
        #pragma unroll
        for (int kt = 0; kt < 4; kt++) {
            f32x4 sA = {}, sB = {};
            #pragma unroll
            for (int ks = 0; ks < 2; ks++) {
                bf16x8 kf = *(const bf16x8*)
                    &Ks[(kt * 16 + lc) * 64 + ((ks * 4 + quad) ^ swz) * 8];
                sA = __builtin_amdgcn_mfma_f32_16x16x32_bf16(kf, qf0[ks], sA, 0, 0, 0);
                sB = __builtin_amdgcn_mfma_f32_16x16x32_bf16(kf, qf1[ks], sB, 0, 0, 0);
            }
            #pragma unroll
            for (int r = 0; r < 4; r++) {
                float pa = __builtin_amdgcn_exp2f(sA[r]);
                float pb = __builtin_amdgcn_exp2f(sB[r]);
                rsum0 += pa; rsum1 += pb;
                pf[kt][0][r] = (short)f2b(pa);
                pf[kt][1][r] = (short)f2b(pb);
            }
        }

        // PV: o[dt][g] += V^T[d][key] * P[key][q]  (K=16, P register-resident)
        #pragma unroll
        for (int dt = 0; dt < 4; dt++) {
            #pragma unroll
            for (int kt = 0; kt < 4; kt++) {
                s16x4 vf = *(const s16x4*)
                    &Vs[(dt * 16 + lc) * 64 +
                        ((2 * kt + (quad >> 1)) ^ swz) * 8 + (quad & 1) * 4];
                o[dt][0] = mfma16(vf, pf[kt][0], o[dt][0]);
                o[dt][1] = mfma16(vf, pf[kt][1], o[dt][1]);
            }
        }
        __builtin_amdgcn_s_setprio(0);
    }

    // denominator: reduce partials across quads (same q = lc)
    rsum0 += __shfl_xor(rsum0, 16); rsum0 += __shfl_xor(rsum0, 32);
    rsum1 += __shfl_xor(rsum1, 16); rsum1 += __shfl_xor(rsum1, 32);
    float inv0 = 1.0f / rsum0, inv1 = 1.0f / rsum1;

    // direct stores: row q = qt*128 + wave*32 + g*16 + lc, cols h*64+dt*16+quad*4
    float* o0 = out + ((size_t)b * SEQ + qt * 128 + wave * 32 + lc) * DIM
                + h * HD + quad * 4;
    float* o1 = o0 + (size_t)16 * DIM;
    #pragma unroll
    for (int dt = 0; dt < 4; dt++) {
        f32x4 s0 = o[dt][0]; s0 *= inv0;
        f32x4 s1 = o[dt][1]; s1 *= inv1;
        *(f32x4*)&o0[dt * 16] = s0;
        *(f32x4*)&o1[dt * 16] = s1;
    }
}

// ---------------------------------------------------------------------------
extern "C" void kernel_launch(void* const* d_in, const int* in_sizes, int n_in,
                              void* d_out, int out_size, void* d_ws, size_t ws_size,
                              hipStream_t stream) {
    (void)in_sizes; (void)n_in; (void)out_size; (void)ws_size;
    const float* x  = (const float*)d_in[0];
    const float* Wq = (const float*)d_in[1];
    const float* bq = (const float*)d_in[2];
    const float* Wk = (const float*)d_in[3];
    const float* bk = (const float*)d_in[4];
    const float* Wv = (const float*)d_in[5];
    const float* bv = (const float*)d_in[6];

    char* ws = (char*)d_ws;
    unsigned short* Wt = (unsigned short*)ws;                             // 6 MB
    unsigned short* Qb = (unsigned short*)(ws + (size_t)6 * 1024 * 1024);
    unsigned short* Kb = Qb + (size_t)BATCH * NH * SEQ * HD;
    unsigned short* Vb = Kb + (size_t)BATCH * NH * SEQ * HD;
    unsigned short* xb = (unsigned short*)d_out;  // scratch; attn overwrites

    cvt_x_k<<<dim3(4096), dim3(256), 0, stream>>>(x, xb);
    transpose_w_k<<<dim3(32, 32, 3), dim3(32, 8), 0, stream>>>(Wq, Wk, Wv, Wt);
    qkv_gemm_k<<<dim3(8, 32, 3), dim3(512), 0, stream>>>(xb, Wt, bq, bk, bv, Qb, Kb, Vb);
    attn_k<<<dim3(1024), dim3(256), 0, stream>>>(Qb, Kb, Vb, (float*)d_out);
}